// Round 2
// baseline (1068.821 us; speedup 1.0000x reference)
//
#include <hip/hip_runtime.h>
#include <stdint.h>

typedef __attribute__((ext_vector_type(8))) short bf16x8;
typedef __attribute__((ext_vector_type(4))) float f32x4;

__device__ __forceinline__ unsigned short f2bf(float f) {
  union { float f; uint32_t u; } v; v.f = f;
  uint32_t r = (v.u + 0x7fffu + ((v.u >> 16) & 1u)) >> 16;
  return (unsigned short)r;
}

// async global->LDS, 16B per lane; LDS dest is wave-uniform base + lane*16 (HW adds it)
__device__ __forceinline__ void async16(const void* g, void* l) {
  __builtin_amdgcn_global_load_lds(
      (const __attribute__((address_space(1))) void*)(uintptr_t)g,
      (__attribute__((address_space(3))) void*)(uint32_t)(uintptr_t)l,
      16, 0, 0);
}

// ---------------- weight transpose fp32(K,N) -> bf16(N,K) ----------------
__global__ __launch_bounds__(256) void transpose_bf16(
    const float* __restrict__ in, unsigned short* __restrict__ out, int N, int K) {
  __shared__ float tile[32][33];
  int tx = threadIdx.x & 31, ty = threadIdx.x >> 5;  // 32 x 8
  int n0 = blockIdx.x * 32, k0 = blockIdx.y * 32;
#pragma unroll
  for (int i = 0; i < 32; i += 8)
    tile[ty + i][tx] = in[(size_t)(k0 + ty + i) * N + n0 + tx];
  __syncthreads();
#pragma unroll
  for (int i = 0; i < 32; i += 8)
    out[(size_t)(n0 + ty + i) * K + k0 + tx] = f2bf(tile[tx][ty + i]);
}

// ---------------- patch gather: maps (B,64,21,21) f32 -> patches (B*49,576) bf16 ----
// patches[b, h*7+w, s1*192+s2*64+c] = maps[b, c, 3h+s1, 3w+s2]
__global__ __launch_bounds__(256) void gather_patches(
    const float* __restrict__ maps, unsigned short* __restrict__ P) {
  int bh = blockIdx.x;
  int b = bh / 7, h = bh % 7;
  __shared__ float lds[4032];  // [c][s1][y] = c*63 + s1*21 + y
  const float* mb = maps + (size_t)b * 64 * 441;
  for (int f = threadIdx.x; f < 4032; f += 256) {
    int c = f / 63, rem = f % 63;
    int s1 = rem / 21, y = rem % 21;
    lds[f] = mb[(size_t)c * 441 + (3 * h + s1) * 21 + y];
  }
  __syncthreads();
  unsigned short* pb = P + ((size_t)b * 49 + (size_t)h * 7) * 576;
#pragma unroll
  for (int w = 0; w < 7; ++w) {
    for (int ep = threadIdx.x; ep < 288; ep += 256) {
      int e = ep * 2;                       // e even -> (c, c+1) same s1,s2
      int c = e & 63, s2 = (e >> 6) % 3, s1 = e / 192;
      float v0 = lds[c * 63 + s1 * 21 + 3 * w + s2];
      float v1 = lds[(c + 1) * 63 + s1 * 21 + 3 * w + s2];
      ushort2 o; o.x = f2bf(v0); o.y = f2bf(v1);
      *(ushort2*)(pb + (size_t)w * 576 + e) = o;
    }
  }
}

// ---------------- tiny-K first layer: H = relu(X @ W1 + b1) -> bf16 -----------------
// X (M,K) f32, W1 (K,1024) f32, 4 rows per block, thread t -> cols 4t..4t+3
__global__ __launch_bounds__(256) void mlp1_small(
    const float* __restrict__ X, const float* __restrict__ W1,
    const float* __restrict__ b1, unsigned short* __restrict__ H, int K) {
  int t = threadIdx.x;
  size_t r0 = (size_t)blockIdx.x * 4;
  float4 bias = ((const float4*)b1)[t];
  float acc[4][4];
#pragma unroll
  for (int rr = 0; rr < 4; ++rr) {
    acc[rr][0] = bias.x; acc[rr][1] = bias.y; acc[rr][2] = bias.z; acc[rr][3] = bias.w;
  }
  for (int k = 0; k < K; ++k) {
    float4 w = ((const float4*)(W1 + (size_t)k * 1024))[t];
#pragma unroll
    for (int rr = 0; rr < 4; ++rr) {
      float x = X[(r0 + rr) * K + k];
      acc[rr][0] = fmaf(x, w.x, acc[rr][0]);
      acc[rr][1] = fmaf(x, w.y, acc[rr][1]);
      acc[rr][2] = fmaf(x, w.z, acc[rr][2]);
      acc[rr][3] = fmaf(x, w.w, acc[rr][3]);
    }
  }
#pragma unroll
  for (int rr = 0; rr < 4; ++rr) {
    ushort4 o;
    o.x = f2bf(fmaxf(acc[rr][0], 0.0f));
    o.y = f2bf(fmaxf(acc[rr][1], 0.0f));
    o.z = f2bf(fmaxf(acc[rr][2], 0.0f));
    o.w = f2bf(fmaxf(acc[rr][3], 0.0f));
    *(ushort4*)(H + (r0 + rr) * 1024 + 4 * t) = o;
  }
}

// ---------------- PE tables: pep (49,1024), pes (32,1024) f32 -----------------------
__global__ __launch_bounds__(256) void pe_kernel(
    const float* __restrict__ sy, float* __restrict__ pep, float* __restrict__ pes) {
  int r = blockIdx.x, i = threadIdx.x;  // i = 0..255
  float f = powf(1.0e-4f, (4.0f * (float)i) / 1024.0f);
  float x, y; float* dst;
  if (r < 49) {
    x = (float)(3 * (r / 7) + 1); y = (float)(3 * (r % 7) + 1);
    dst = pep + (size_t)r * 1024;
  } else {
    int s = r - 49;
    x = sy[s * 8 + 0]; y = sy[s * 8 + 1];
    dst = pes + (size_t)s * 1024;
  }
  float sx, cx, syv, cyv;
  sincosf(x * f, &sx, &cx);
  sincosf(y * f, &syv, &cyv);
  dst[2 * i] = sx; dst[2 * i + 1] = cx;
  dst[512 + 2 * i] = syv; dst[512 + 2 * i + 1] = cyv;
}

// ---------------- MFMA GEMM: C = A(M,K) @ Bt(1024,K)^T + bias ----------------------
// mode 0: relu -> bf16 into outb (M,1024)
// mode 1: +pe[row%rp], scatter fp32 into outf at row (row/rp)*82 + col_base + row%rp
__global__ __launch_bounds__(256) void gemm_bf16(
    const unsigned short* __restrict__ A, const unsigned short* __restrict__ Bt,
    const float* __restrict__ bias, const float* __restrict__ pe,
    unsigned short* __restrict__ outb, float* __restrict__ outf,
    int M, int K, int mode, int rp, int col_base) {
  __shared__ unsigned short As[128 * 32];
  __shared__ unsigned short Bs[128 * 32];
  const int t = threadIdx.x;
  const int wave = t >> 6, lane = t & 63;
  const int lane15 = lane & 15, quad = lane >> 4;
  const int wm = wave >> 1, wn = wave & 1;
  const int bn = blockIdx.x, bm = blockIdx.y;
  const size_t rA0 = (size_t)bm * 128;
  const size_t rB0 = (size_t)bn * 128;
  const int sr = lane >> 2;          // row within 16-row segment
  const int sk = (lane & 3) * 8;     // k-element offset (8 bf16 = 16B)
  f32x4 acc[4][4] = {};

  for (int k0 = 0; k0 < K; k0 += 32) {
#pragma unroll
    for (int q = 0; q < 4; ++q) {
      int seg = wave * 4 + q;        // wave-uniform
      if (seg < 8) {
        async16(A + (rA0 + seg * 16 + sr) * (size_t)K + k0 + sk, (char*)As + seg * 1024);
      } else {
        int s2 = seg - 8;
        async16(Bt + (rB0 + s2 * 16 + sr) * (size_t)K + k0 + sk, (char*)Bs + s2 * 1024);
      }
    }
    __syncthreads();
    bf16x8 av[4], bv[4];
#pragma unroll
    for (int i = 0; i < 4; ++i)
      av[i] = *(const bf16x8*)&As[(wm * 64 + i * 16 + lane15) * 32 + quad * 8];
#pragma unroll
    for (int j = 0; j < 4; ++j)
      bv[j] = *(const bf16x8*)&Bs[(wn * 64 + j * 16 + lane15) * 32 + quad * 8];
#pragma unroll
    for (int i = 0; i < 4; ++i)
#pragma unroll
      for (int j = 0; j < 4; ++j)
        acc[i][j] = __builtin_amdgcn_mfma_f32_16x16x32_bf16(av[i], bv[j], acc[i][j], 0, 0, 0);
    __syncthreads();
  }

  const int gc0 = bn * 128 + wn * 64 + lane15;
  if (mode == 0) {
#pragma unroll
    for (int i = 0; i < 4; ++i) {
      int gr0 = bm * 128 + wm * 64 + i * 16 + quad * 4;
#pragma unroll
      for (int r = 0; r < 4; ++r) {
        size_t row = (size_t)(gr0 + r);
#pragma unroll
        for (int j = 0; j < 4; ++j) {
          int col = gc0 + j * 16;
          float v = acc[i][j][r] + bias[col];
          outb[row * 1024 + col] = f2bf(fmaxf(v, 0.0f));
        }
      }
    }
  } else {
#pragma unroll
    for (int i = 0; i < 4; ++i) {
      int gr0 = bm * 128 + wm * 64 + i * 16 + quad * 4;
#pragma unroll
      for (int r = 0; r < 4; ++r) {
        int row = gr0 + r;
        int bb = row / rp;
        int p = row - bb * rp;
        size_t orow = (size_t)bb * 82 + (size_t)col_base + (size_t)p;
#pragma unroll
        for (int j = 0; j < 4; ++j) {
          int col = gc0 + j * 16;
          float v = acc[i][j][r] + bias[col];
          if (pe) v += pe[(size_t)p * 1024 + col];
          outf[orow * 1024 + col] = v;
        }
      }
    }
  }
}

extern "C" void kernel_launch(void* const* d_in, const int* in_sizes, int n_in,
                              void* d_out, int out_size, void* d_ws, size_t ws_size,
                              hipStream_t stream) {
  const float* maps = (const float*)d_in[0];
  const float* sy   = (const float*)d_in[1];
  const float* gs   = (const float*)d_in[2];
  const float* Wp1  = (const float*)d_in[3];
  const float* bp1  = (const float*)d_in[4];
  const float* Wp2  = (const float*)d_in[5];
  const float* bp2  = (const float*)d_in[6];
  const float* Ws1  = (const float*)d_in[7];
  const float* bs1  = (const float*)d_in[8];
  const float* Ws2  = (const float*)d_in[9];
  const float* bs2  = (const float*)d_in[10];
  const float* Wg1  = (const float*)d_in[11];
  const float* bg1  = (const float*)d_in[12];
  const float* Wg2  = (const float*)d_in[13];
  const float* bg2  = (const float*)d_in[14];
  float* out = (float*)d_out;

  const int B  = in_sizes[0] / (64 * 21 * 21);  // 1024
  const int Mp = B * 49;                        // 50176 (128 | Mp)
  const int Ms = B * 32;                        // 32768
  const int Mg = B;                             // 1024

  char* p = (char*)d_ws;
  auto alloc = [&](size_t bytes) { char* r = p; p += (bytes + 255) & ~(size_t)255; return r; };
  unsigned short* pat  = (unsigned short*)alloc((size_t)Mp * 576 * 2);
  unsigned short* hp   = (unsigned short*)alloc((size_t)Mp * 1024 * 2);
  unsigned short* hs   = (unsigned short*)alloc((size_t)Ms * 1024 * 2);
  unsigned short* hg   = (unsigned short*)alloc((size_t)Mg * 1024 * 2);
  unsigned short* wp1t = (unsigned short*)alloc((size_t)1024 * 576 * 2);
  unsigned short* wp2t = (unsigned short*)alloc((size_t)1024 * 1024 * 2);
  unsigned short* ws2t = (unsigned short*)alloc((size_t)1024 * 1024 * 2);
  unsigned short* wg2t = (unsigned short*)alloc((size_t)1024 * 1024 * 2);
  float* pep = (float*)alloc((size_t)49 * 1024 * 4);
  float* pes = (float*)alloc((size_t)32 * 1024 * 4);

  // weights -> transposed bf16 (Bt layout, N x K)
  transpose_bf16<<<dim3(1024 / 32, 576 / 32), 256, 0, stream>>>(Wp1, wp1t, 1024, 576);
  transpose_bf16<<<dim3(32, 32), 256, 0, stream>>>(Wp2, wp2t, 1024, 1024);
  transpose_bf16<<<dim3(32, 32), 256, 0, stream>>>(Ws2, ws2t, 1024, 1024);
  transpose_bf16<<<dim3(32, 32), 256, 0, stream>>>(Wg2, wg2t, 1024, 1024);

  // patch gather -> bf16
  gather_patches<<<B * 7, 256, 0, stream>>>(maps, pat);

  // tiny-K first layers
  mlp1_small<<<Ms / 4, 256, 0, stream>>>(sy, Ws1, bs1, hs, 8);
  mlp1_small<<<Mg / 4, 256, 0, stream>>>(gs, Wg1, bg1, hg, 16);

  // positional-encoding tables
  pe_kernel<<<81, 256, 0, stream>>>(sy, pep, pes);

  // big MFMA GEMMs
  gemm_bf16<<<dim3(8, Mp / 128), 256, 0, stream>>>(pat, wp1t, bp1, nullptr, hp, nullptr, Mp, 576, 0, 0, 0);
  gemm_bf16<<<dim3(8, Mp / 128), 256, 0, stream>>>(hp, wp2t, bp2, pep, nullptr, out, Mp, 1024, 1, 49, 33);
  gemm_bf16<<<dim3(8, Ms / 128), 256, 0, stream>>>(hs, ws2t, bs2, pes, nullptr, out, Ms, 1024, 1, 32, 0);
  gemm_bf16<<<dim3(8, Mg / 128), 256, 0, stream>>>(hg, wg2t, bg2, nullptr, nullptr, out, Mg, 1024, 1, 1, 32);

  (void)n_in; (void)out_size; (void)ws_size;
}